// Round 10
// baseline (105.052 us; speedup 1.0000x reference)
//
#include <hip/hip_runtime.h>
#include <hip/hip_fp16.h>
#include <math.h>

// Chamfer distance, B=4, N=M=8192, D=3, fp32, via f16 MFMA — SYMMETRIC d^2,
// DOUBLE-COMPUTE: every 32x32 tile is computed twice (once per direction) so
// BOTH directions' min-reductions are 16 independent register fminf updates.
// MFMA cost doubles (0.85 -> 1.7 us device-wide, irrelevant); the serial
// col-min v_min3 chain + LDS atomics of R7-R9 disappear entirely.
//
// K=16 slot packing (A side | B side), unchanged from R9 (measured absmax 0.0):
//  k0-2 : h(-2p)xyz        | h(q)xyz           (hi*hi cross)
//  k3-5 : l(-2p)xyz*2^8    | h(q)xyz*2^-8      (lo*hi)
//  k6   : h(p^2)           | 1
//  k7   : 1                | h(q^2)
//  k8-10: h(-2p)xyz*2^-8   | l(q)xyz*2^8       (hi*lo)
//  k11  : l(p^2)           | 1
//  k12  : 1                | l(q^2)            (dropped l*l ~2^-24)
//
// Block = (batch, ichunk, jchunk) 256x256 sub-block. Pass 1: rows=a, stream
// 8 b-record tiles -> rm. Pass 2: rows=b, stream 8 a-record tiles -> cm.
// Epilogue: wave-private stride-33 LDS transpose (aliases dead records),
// 4 sub-passes (rm0, rm1, cm0, cm1). Kernel B: min 32 partials/dir, clamp,
// mean, atomicAdd.

#define BATCH   4
#define NPTS    8192
#define THREADS 256
#define NCH     32            // 256-point chunks per cloud
#define SC      256.0f
#define ISC     (1.0f/256.0f)
#define FLT_BIG 3.4e38f

typedef _Float16 half8 __attribute__((ext_vector_type(8)));
typedef float f32x16 __attribute__((ext_vector_type(16)));

union U4H8 { uint4 u; half8 h; };

__device__ __forceinline__ unsigned pk(__half lo, __half hi) {
    return (unsigned)__half_as_ushort(lo) | ((unsigned)__half_as_ushort(hi) << 16);
}

// B-operand-format record for point q (coords +q, norm q^2 in the B slots)
__device__ __forceinline__ void make_rec(const float* __restrict__ src,
                                         unsigned* __restrict__ g0d,
                                         unsigned* __restrict__ g1d) {
    const __half one = __float2half(1.0f);
    const __half z0  = __float2half(0.0f);
    const float x = src[0], y = src[1], z = src[2];
    __half hx = __float2half(x), hy = __float2half(y), hz = __float2half(z);
    __half lx = __float2half((x - __half2float(hx)) * SC);
    __half ly = __float2half((y - __half2float(hy)) * SC);
    __half lz = __float2half((z - __half2float(hz)) * SC);
    __half sx = __float2half(__half2float(hx) * ISC);
    __half sy = __float2half(__half2float(hy) * ISC);
    __half sz = __float2half(__half2float(hz) * ISC);
    const float q2 = fmaf(x, x, fmaf(y, y, z * z));
    __half hq2 = __float2half(q2);
    __half lq2 = __float2half(q2 - __half2float(hq2));
    *(uint4*)g0d = make_uint4(pk(hx, hy), pk(hz, sx), pk(sy, sz), pk(one, hq2));
    *(uint4*)g1d = make_uint4(pk(lx, ly), pk(lz, one), pk(lq2, z0), pk(z0, z0));
}

// A-operand-format fragment for point p (coords -2p, norm p^2 in the A slots)
__device__ __forceinline__ U4H8 make_afrag(const float* __restrict__ ap, int g) {
    const __half one = __float2half(1.0f);
    const __half z0  = __float2half(0.0f);
    const float x = ap[0], y = ap[1], z = ap[2];
    const float vx = -2.0f * x, vy = -2.0f * y, vz = -2.0f * z;
    __half Hx = __float2half(vx), Hy = __float2half(vy), Hz = __float2half(vz);
    __half Lx = __float2half((vx - __half2float(Hx)) * SC);
    __half Ly = __float2half((vy - __half2float(Hy)) * SC);
    __half Lz = __float2half((vz - __half2float(Hz)) * SC);
    __half Sx = __float2half(__half2float(Hx) * ISC);
    __half Sy = __float2half(__half2float(Hy) * ISC);
    __half Sz = __float2half(__half2float(Hz) * ISC);
    const float p2 = fmaf(x, x, fmaf(y, y, z * z));
    __half hp2 = __float2half(p2);
    __half lp2 = __float2half(p2 - __half2float(hp2));
    U4H8 A;
    if (g == 0)
        A.u = make_uint4(pk(Hx, Hy), pk(Hz, Lx), pk(Ly, Lz), pk(hp2, one));
    else
        A.u = make_uint4(pk(Sx, Sy), pk(Sz, lp2), pk(one, z0), pk(z0, z0));
    return A;
}

__global__ void chamfer_mfma_kernel(
        const float* __restrict__ pc1, const float* __restrict__ pc2,
        float* __restrict__ part_row, float* __restrict__ part_col,
        float* __restrict__ out) {
    const int bid    = blockIdx.x;       // 4096 = batch*1024 + ichunk*32 + jchunk
    const int jchunk = bid & 31;
    const int ichunk = (bid >> 5) & 31;
    const int batch  = bid >> 10;

    if (bid == 0 && threadIdx.x < BATCH) out[threadIdx.x] = 0.0f;

    // LDS dwords: brecs [0..2047] (g0 p*4, g1 1024+p*4), arecs [2048..4095];
    // epilogue scratch [0..4223] (4 waves x 1056) aliases dead records.
    __shared__ unsigned smem[4224];
    unsigned* brecs = smem;
    unsigned* arecs = smem + 2048;

    const int t = threadIdx.x;
    const int L = t & 63;
    const int w = t >> 6;
    const int g = L >> 5;
    const int col = L & 31;

    const float* abase = pc1 + (size_t)batch * NPTS * 3;
    const float* bbase = pc2 + (size_t)batch * NPTS * 3;
    const int i0 = ichunk * 256, j0 = jchunk * 256;

    // ---- cooperative stage: both record sets ----
    make_rec(bbase + 3 * (j0 + t), &brecs[t * 4], &brecs[1024 + t * 4]);
    make_rec(abase + 3 * (i0 + t), &arecs[t * 4], &arecs[1024 + t * 4]);

    // ---- pass-1 A-frags from a-points (rows i0 + w*64 + col + {0,32}) ----
    U4H8 A0 = make_afrag(abase + 3 * (i0 + w * 64 + col), g);
    U4H8 A1 = make_afrag(abase + 3 * (i0 + w * 64 + col + 32), g);

    float rm0[16], rm1[16];
    #pragma unroll
    for (int r = 0; r < 16; ++r) { rm0[r] = FLT_BIG; rm1[r] = FLT_BIG; }

    __syncthreads();

    const f32x16 zf = {0.0f};
    const int fb = g * 1024 + col * 4;

    // ---- pass 1: stream b-record tiles, rows = a ----
    {
        U4H8 nb; nb.u = *(const uint4*)&brecs[fb];
        #pragma unroll 2
        for (int jt = 0; jt < 8; ++jt) {
            const U4H8 b = nb;
            if (jt < 7) nb.u = *(const uint4*)&brecs[fb + (jt + 1) * 128];
            f32x16 d0 = __builtin_amdgcn_mfma_f32_32x32x16_f16(A0.h, b.h, zf, 0, 0, 0);
            f32x16 d1 = __builtin_amdgcn_mfma_f32_32x32x16_f16(A1.h, b.h, zf, 0, 0, 0);
            #pragma unroll
            for (int r = 0; r < 16; ++r) {
                rm0[r] = fminf(rm0[r], d0[r]);
                rm1[r] = fminf(rm1[r], d1[r]);
            }
        }
    }

    // ---- pass-2 A-frags from b-points; stream a-record tiles, rows = b ----
    A0 = make_afrag(bbase + 3 * (j0 + w * 64 + col), g);
    A1 = make_afrag(bbase + 3 * (j0 + w * 64 + col + 32), g);

    float cm0[16], cm1[16];
    #pragma unroll
    for (int r = 0; r < 16; ++r) { cm0[r] = FLT_BIG; cm1[r] = FLT_BIG; }

    {
        U4H8 na; na.u = *(const uint4*)&arecs[fb];
        #pragma unroll 2
        for (int it = 0; it < 8; ++it) {
            const U4H8 a = na;
            if (it < 7) na.u = *(const uint4*)&arecs[fb + (it + 1) * 128];
            f32x16 d0 = __builtin_amdgcn_mfma_f32_32x32x16_f16(A0.h, a.h, zf, 0, 0, 0);
            f32x16 d1 = __builtin_amdgcn_mfma_f32_32x32x16_f16(A1.h, a.h, zf, 0, 0, 0);
            #pragma unroll
            for (int r = 0; r < 16; ++r) {
                cm0[r] = fminf(cm0[r], d0[r]);
                cm1[r] = fminf(cm1[r], d1[r]);
            }
        }
    }

    __syncthreads();   // all record reads done; scratch may alias records

    // ---- epilogue: wave-private 32x33 transpose, 4 sub-passes ----
    float* sf = (float*)smem;
    const int wbase = w * 1056;
    const int rrow = col;                // lane's read row
    const int ch   = L >> 5;             // 16-col half selector

    float* dst[4];
    dst[0] = part_row + ((size_t)batch * NCH + jchunk) * NPTS + i0 + w * 64;
    dst[1] = dst[0] + 32;
    dst[2] = part_col + ((size_t)batch * NCH + ichunk) * NPTS + j0 + w * 64;
    dst[3] = dst[2] + 32;
    const float* accs[4] = {rm0, rm1, cm0, cm1};

    #pragma unroll
    for (int p = 0; p < 4; ++p) {
        const float* acc = accs[p];
        #pragma unroll
        for (int r = 0; r < 16; ++r) {
            const int row0 = (r & 3) + 8 * (r >> 2) + 4 * g;
            sf[wbase + row0 * 33 + col] = acc[r];
        }
        const float* rp = &sf[wbase + rrow * 33 + ch * 16];
        float v = rp[0];
        #pragma unroll
        for (int i = 1; i < 16; ++i) v = fminf(v, rp[i]);
        v = fminf(v, __shfl_xor(v, 32, 64));
        if (L < 32) dst[p][L] = v;
    }
}

__global__ __launch_bounds__(THREADS) void chamfer_reduce_kernel(
        const float* __restrict__ part_row, const float* __restrict__ part_col,
        float* __restrict__ out) {
    const int idx   = blockIdx.x * THREADS + threadIdx.x;   // 0..65535
    const int dir   = idx >> 15;
    const int batch = (idx >> 13) & 3;
    const int n     = idx & (NPTS - 1);

    const float* pb = (dir == 0 ? part_row : part_col) + (size_t)batch * NCH * NPTS + n;
    float m0 = FLT_BIG, m1 = FLT_BIG, m2 = FLT_BIG, m3 = FLT_BIG;
    #pragma unroll
    for (int s = 0; s < NCH; s += 4) {
        m0 = fminf(m0, pb[(size_t)(s + 0) * NPTS]);
        m1 = fminf(m1, pb[(size_t)(s + 1) * NPTS]);
        m2 = fminf(m2, pb[(size_t)(s + 2) * NPTS]);
        m3 = fminf(m3, pb[(size_t)(s + 3) * NPTS]);
    }
    float d2 = fmaxf(fminf(fminf(m0, m1), fminf(m2, m3)), 0.0f);

    #pragma unroll
    for (int off = 32; off > 0; off >>= 1)
        d2 += __shfl_down(d2, off, 64);

    __shared__ float wsum[THREADS / 64];
    if ((threadIdx.x & 63) == 0) wsum[threadIdx.x >> 6] = d2;
    __syncthreads();

    if (threadIdx.x == 0) {
        float ssum = 0.0f;
        #pragma unroll
        for (int wv = 0; wv < THREADS / 64; ++wv) ssum += wsum[wv];
        atomicAdd(&out[batch], ssum * (1.0f / (float)NPTS));
    }
}

extern "C" void kernel_launch(void* const* d_in, const int* in_sizes, int n_in,
                              void* d_out, int out_size, void* d_ws, size_t ws_size,
                              hipStream_t stream) {
    const float* pc1 = (const float*)d_in[0];
    const float* pc2 = (const float*)d_in[1];
    float* out      = (float*)d_out;
    float* part_row = (float*)d_ws;                              // 4 MB
    float* part_col = part_row + (size_t)BATCH * NCH * NPTS;     // 4 MB

    chamfer_mfma_kernel<<<BATCH * NCH * NCH, THREADS, 0, stream>>>(
        pc1, pc2, part_row, part_col, out);
    chamfer_reduce_kernel<<<(2 * BATCH * NPTS) / THREADS, THREADS, 0, stream>>>(
        part_row, part_col, out);
}

// Round 11
// 104.332 us; speedup vs baseline: 1.0069x; 1.0069x over previous
//
#include <hip/hip_runtime.h>
#include <hip/hip_fp16.h>
#include <math.h>

// Chamfer distance, B=4, N=M=8192, D=3, fp32, via f16 MFMA — SYMMETRIC d^2,
// DOUBLE-COMPUTE: every 32x32 tile computed twice (once per direction) so BOTH
// directions' min-reductions are 16 independent register fminf updates.
//
// ROUND-11 FIX of R10: the epilogue used `const float* accs[4] = {rm0,...}` —
// taking pointers to register arrays forced ALL accumulators to scratch
// (VGPR_Count 64, 78 MB HBM writes, 52 us). Epilogue is now a macro with
// direct array names; no pointer indirection touches rm*/cm*.
//
// K=16 slot packing (A side | B side), measured absmax 0.0:
//  k0-2 : h(-2p)xyz        | h(q)xyz           (hi*hi cross)
//  k3-5 : l(-2p)xyz*2^8    | h(q)xyz*2^-8      (lo*hi)
//  k6   : h(p^2)           | 1
//  k7   : 1                | h(q^2)
//  k8-10: h(-2p)xyz*2^-8   | l(q)xyz*2^8       (hi*lo)
//  k11  : l(p^2)           | 1
//  k12  : 1                | l(q^2)            (dropped l*l ~2^-24)

#define BATCH   4
#define NPTS    8192
#define THREADS 256
#define NCH     32            // 256-point chunks per cloud
#define SC      256.0f
#define ISC     (1.0f/256.0f)
#define FLT_BIG 3.4e38f

typedef _Float16 half8 __attribute__((ext_vector_type(8)));
typedef float f32x16 __attribute__((ext_vector_type(16)));

union U4H8 { uint4 u; half8 h; };

__device__ __forceinline__ unsigned pk(__half lo, __half hi) {
    return (unsigned)__half_as_ushort(lo) | ((unsigned)__half_as_ushort(hi) << 16);
}

// B-operand-format record for point q (coords +q, norm q^2 in the B slots)
__device__ __forceinline__ void make_rec(const float* __restrict__ src,
                                         unsigned* __restrict__ g0d,
                                         unsigned* __restrict__ g1d) {
    const __half one = __float2half(1.0f);
    const __half z0  = __float2half(0.0f);
    const float x = src[0], y = src[1], z = src[2];
    __half hx = __float2half(x), hy = __float2half(y), hz = __float2half(z);
    __half lx = __float2half((x - __half2float(hx)) * SC);
    __half ly = __float2half((y - __half2float(hy)) * SC);
    __half lz = __float2half((z - __half2float(hz)) * SC);
    __half sx = __float2half(__half2float(hx) * ISC);
    __half sy = __float2half(__half2float(hy) * ISC);
    __half sz = __float2half(__half2float(hz) * ISC);
    const float q2 = fmaf(x, x, fmaf(y, y, z * z));
    __half hq2 = __float2half(q2);
    __half lq2 = __float2half(q2 - __half2float(hq2));
    *(uint4*)g0d = make_uint4(pk(hx, hy), pk(hz, sx), pk(sy, sz), pk(one, hq2));
    *(uint4*)g1d = make_uint4(pk(lx, ly), pk(lz, one), pk(lq2, z0), pk(z0, z0));
}

// A-operand-format fragment for point p (coords -2p, norm p^2 in the A slots)
__device__ __forceinline__ U4H8 make_afrag(const float* __restrict__ ap, int g) {
    const __half one = __float2half(1.0f);
    const __half z0  = __float2half(0.0f);
    const float x = ap[0], y = ap[1], z = ap[2];
    const float vx = -2.0f * x, vy = -2.0f * y, vz = -2.0f * z;
    __half Hx = __float2half(vx), Hy = __float2half(vy), Hz = __float2half(vz);
    __half Lx = __float2half((vx - __half2float(Hx)) * SC);
    __half Ly = __float2half((vy - __half2float(Hy)) * SC);
    __half Lz = __float2half((vz - __half2float(Hz)) * SC);
    __half Sx = __float2half(__half2float(Hx) * ISC);
    __half Sy = __float2half(__half2float(Hy) * ISC);
    __half Sz = __float2half(__half2float(Hz) * ISC);
    const float p2 = fmaf(x, x, fmaf(y, y, z * z));
    __half hp2 = __float2half(p2);
    __half lp2 = __float2half(p2 - __half2float(hp2));
    U4H8 A;
    if (g == 0)
        A.u = make_uint4(pk(Hx, Hy), pk(Hz, Lx), pk(Ly, Lz), pk(hp2, one));
    else
        A.u = make_uint4(pk(Sx, Sy), pk(Sz, lp2), pk(one, z0), pk(z0, z0));
    return A;
}

// Wave-private 32x33-stride LDS transpose + row-min + store. acc is a register
// array NAME (no pointer is formed); dstp is a float* expression.
#define EPILOGUE(acc, dstp)                                                   \
    {                                                                         \
        _Pragma("unroll")                                                     \
        for (int r = 0; r < 16; ++r) {                                        \
            const int row0 = (r & 3) + 8 * (r >> 2) + 4 * g;                  \
            sf[wbase + row0 * 33 + col] = acc[r];                             \
        }                                                                     \
        const float* rp = &sf[wbase + col * 33 + ch * 16];                    \
        float v = rp[0];                                                      \
        _Pragma("unroll")                                                     \
        for (int i = 1; i < 16; ++i) v = fminf(v, rp[i]);                     \
        v = fminf(v, __shfl_xor(v, 32, 64));                                  \
        if (L < 32) (dstp)[L] = v;                                            \
    }

__global__ void chamfer_mfma_kernel(
        const float* __restrict__ pc1, const float* __restrict__ pc2,
        float* __restrict__ part_row, float* __restrict__ part_col,
        float* __restrict__ out) {
    const int bid    = blockIdx.x;       // 4096 = batch*1024 + ichunk*32 + jchunk
    const int jchunk = bid & 31;
    const int ichunk = (bid >> 5) & 31;
    const int batch  = bid >> 10;

    if (bid == 0 && threadIdx.x < BATCH) out[threadIdx.x] = 0.0f;

    // LDS dwords: brecs [0..2047] (g0 p*4, g1 1024+p*4), arecs [2048..4095];
    // epilogue scratch [0..4223] (4 waves x 1056) aliases dead records.
    __shared__ unsigned smem[4224];
    unsigned* brecs = smem;
    unsigned* arecs = smem + 2048;

    const int t = threadIdx.x;
    const int L = t & 63;
    const int w = t >> 6;
    const int g = L >> 5;
    const int col = L & 31;
    const int ch = L >> 5;

    const float* abase = pc1 + (size_t)batch * NPTS * 3;
    const float* bbase = pc2 + (size_t)batch * NPTS * 3;
    const int i0 = ichunk * 256, j0 = jchunk * 256;

    // ---- cooperative stage: both record sets ----
    make_rec(bbase + 3 * (j0 + t), &brecs[t * 4], &brecs[1024 + t * 4]);
    make_rec(abase + 3 * (i0 + t), &arecs[t * 4], &arecs[1024 + t * 4]);

    // ---- pass-1 A-frags from a-points (rows i0 + w*64 + col + {0,32}) ----
    U4H8 A0 = make_afrag(abase + 3 * (i0 + w * 64 + col), g);
    U4H8 A1 = make_afrag(abase + 3 * (i0 + w * 64 + col + 32), g);

    float rm0[16], rm1[16];
    #pragma unroll
    for (int r = 0; r < 16; ++r) { rm0[r] = FLT_BIG; rm1[r] = FLT_BIG; }

    __syncthreads();

    const f32x16 zf = {0.0f};
    const int fb = g * 1024 + col * 4;

    // ---- pass 1: stream b-record tiles, rows = a ----
    {
        U4H8 nb; nb.u = *(const uint4*)&brecs[fb];
        #pragma unroll 2
        for (int jt = 0; jt < 8; ++jt) {
            const U4H8 b = nb;
            if (jt < 7) nb.u = *(const uint4*)&brecs[fb + (jt + 1) * 128];
            f32x16 d0 = __builtin_amdgcn_mfma_f32_32x32x16_f16(A0.h, b.h, zf, 0, 0, 0);
            f32x16 d1 = __builtin_amdgcn_mfma_f32_32x32x16_f16(A1.h, b.h, zf, 0, 0, 0);
            #pragma unroll
            for (int r = 0; r < 16; ++r) {
                rm0[r] = fminf(rm0[r], d0[r]);
                rm1[r] = fminf(rm1[r], d1[r]);
            }
        }
    }

    // ---- pass-2 A-frags from b-points; stream a-record tiles, rows = b ----
    A0 = make_afrag(bbase + 3 * (j0 + w * 64 + col), g);
    A1 = make_afrag(bbase + 3 * (j0 + w * 64 + col + 32), g);

    float cm0[16], cm1[16];
    #pragma unroll
    for (int r = 0; r < 16; ++r) { cm0[r] = FLT_BIG; cm1[r] = FLT_BIG; }

    {
        U4H8 na; na.u = *(const uint4*)&arecs[fb];
        #pragma unroll 2
        for (int it = 0; it < 8; ++it) {
            const U4H8 a = na;
            if (it < 7) na.u = *(const uint4*)&arecs[fb + (it + 1) * 128];
            f32x16 d0 = __builtin_amdgcn_mfma_f32_32x32x16_f16(A0.h, a.h, zf, 0, 0, 0);
            f32x16 d1 = __builtin_amdgcn_mfma_f32_32x32x16_f16(A1.h, a.h, zf, 0, 0, 0);
            #pragma unroll
            for (int r = 0; r < 16; ++r) {
                cm0[r] = fminf(cm0[r], d0[r]);
                cm1[r] = fminf(cm1[r], d1[r]);
            }
        }
    }

    __syncthreads();   // all record reads done; scratch may alias records

    // ---- epilogue: 4 sub-passes, no pointer indirection on accumulators ----
    float* sf = (float*)smem;
    const int wbase = w * 1056;

    float* dr = part_row + ((size_t)batch * NCH + jchunk) * NPTS + i0 + w * 64;
    float* dc = part_col + ((size_t)batch * NCH + ichunk) * NPTS + j0 + w * 64;

    EPILOGUE(rm0, dr);
    EPILOGUE(rm1, dr + 32);
    EPILOGUE(cm0, dc);
    EPILOGUE(cm1, dc + 32);
}

__global__ __launch_bounds__(THREADS) void chamfer_reduce_kernel(
        const float* __restrict__ part_row, const float* __restrict__ part_col,
        float* __restrict__ out) {
    const int idx   = blockIdx.x * THREADS + threadIdx.x;   // 0..65535
    const int dir   = idx >> 15;
    const int batch = (idx >> 13) & 3;
    const int n     = idx & (NPTS - 1);

    const float* pb = (dir == 0 ? part_row : part_col) + (size_t)batch * NCH * NPTS + n;
    float m0 = FLT_BIG, m1 = FLT_BIG, m2 = FLT_BIG, m3 = FLT_BIG;
    #pragma unroll
    for (int s = 0; s < NCH; s += 4) {
        m0 = fminf(m0, pb[(size_t)(s + 0) * NPTS]);
        m1 = fminf(m1, pb[(size_t)(s + 1) * NPTS]);
        m2 = fminf(m2, pb[(size_t)(s + 2) * NPTS]);
        m3 = fminf(m3, pb[(size_t)(s + 3) * NPTS]);
    }
    float d2 = fmaxf(fminf(fminf(m0, m1), fminf(m2, m3)), 0.0f);

    #pragma unroll
    for (int off = 32; off > 0; off >>= 1)
        d2 += __shfl_down(d2, off, 64);

    __shared__ float wsum[THREADS / 64];
    if ((threadIdx.x & 63) == 0) wsum[threadIdx.x >> 6] = d2;
    __syncthreads();

    if (threadIdx.x == 0) {
        float ssum = 0.0f;
        #pragma unroll
        for (int wv = 0; wv < THREADS / 64; ++wv) ssum += wsum[wv];
        atomicAdd(&out[batch], ssum * (1.0f / (float)NPTS));
    }
}

extern "C" void kernel_launch(void* const* d_in, const int* in_sizes, int n_in,
                              void* d_out, int out_size, void* d_ws, size_t ws_size,
                              hipStream_t stream) {
    const float* pc1 = (const float*)d_in[0];
    const float* pc2 = (const float*)d_in[1];
    float* out      = (float*)d_out;
    float* part_row = (float*)d_ws;                              // 4 MB
    float* part_col = part_row + (size_t)BATCH * NCH * NPTS;     // 4 MB

    chamfer_mfma_kernel<<<BATCH * NCH * NCH, THREADS, 0, stream>>>(
        pc1, pc2, part_row, part_col, out);
    chamfer_reduce_kernel<<<(2 * BATCH * NPTS) / THREADS, THREADS, 0, stream>>>(
        part_row, part_col, out);
}

// Round 12
// 97.238 us; speedup vs baseline: 1.0804x; 1.0730x over previous
//
#include <hip/hip_runtime.h>
#include <hip/hip_fp16.h>
#include <math.h>

// Chamfer distance, B=4, N=M=8192, D=3, fp32, via f16 MFMA — SYMMETRIC d^2,
// DOUBLE-COMPUTE: every 32x32 tile computed twice (once per direction) so BOTH
// directions' min-reductions are 16 independent register fminf updates.
//
// ROUND-12 FIX of R10/R11 spill: kernels WITHOUT __launch_bounds__ default to
// amdgpu-flat-work-group-size=1,1024 -> 16 waves/WG must fit one CU -> 4
// waves/SIMD minimum -> 128-reg cap (64 arch VGPR + 64 AGPR observed) ->
// ~50 dwords/thread scratch spill (78 MB HBM writes). __launch_bounds__(256)
// (block-size arg ONLY — R8 showed the waves-per-EU arg forces AGPR spills)
// restores the full 512-reg budget.
//
// K=16 slot packing (A side | B side), measured absmax 0.0:
//  k0-2 : h(-2p)xyz        | h(q)xyz           (hi*hi cross)
//  k3-5 : l(-2p)xyz*2^8    | h(q)xyz*2^-8      (lo*hi)
//  k6   : h(p^2)           | 1
//  k7   : 1                | h(q^2)
//  k8-10: h(-2p)xyz*2^-8   | l(q)xyz*2^8       (hi*lo)
//  k11  : l(p^2)           | 1
//  k12  : 1                | l(q^2)            (dropped l*l ~2^-24)

#define BATCH   4
#define NPTS    8192
#define THREADS 256
#define NCH     32            // 256-point chunks per cloud
#define SC      256.0f
#define ISC     (1.0f/256.0f)
#define FLT_BIG 3.4e38f

typedef _Float16 half8 __attribute__((ext_vector_type(8)));
typedef float f32x16 __attribute__((ext_vector_type(16)));

union U4H8 { uint4 u; half8 h; };

__device__ __forceinline__ unsigned pk(__half lo, __half hi) {
    return (unsigned)__half_as_ushort(lo) | ((unsigned)__half_as_ushort(hi) << 16);
}

// B-operand-format record for point q (coords +q, norm q^2 in the B slots)
__device__ __forceinline__ void make_rec(const float* __restrict__ src,
                                         unsigned* __restrict__ g0d,
                                         unsigned* __restrict__ g1d) {
    const __half one = __float2half(1.0f);
    const __half z0  = __float2half(0.0f);
    const float x = src[0], y = src[1], z = src[2];
    __half hx = __float2half(x), hy = __float2half(y), hz = __float2half(z);
    __half lx = __float2half((x - __half2float(hx)) * SC);
    __half ly = __float2half((y - __half2float(hy)) * SC);
    __half lz = __float2half((z - __half2float(hz)) * SC);
    __half sx = __float2half(__half2float(hx) * ISC);
    __half sy = __float2half(__half2float(hy) * ISC);
    __half sz = __float2half(__half2float(hz) * ISC);
    const float q2 = fmaf(x, x, fmaf(y, y, z * z));
    __half hq2 = __float2half(q2);
    __half lq2 = __float2half(q2 - __half2float(hq2));
    *(uint4*)g0d = make_uint4(pk(hx, hy), pk(hz, sx), pk(sy, sz), pk(one, hq2));
    *(uint4*)g1d = make_uint4(pk(lx, ly), pk(lz, one), pk(lq2, z0), pk(z0, z0));
}

// A-operand-format fragment for point p (coords -2p, norm p^2 in the A slots)
__device__ __forceinline__ U4H8 make_afrag(const float* __restrict__ ap, int g) {
    const __half one = __float2half(1.0f);
    const __half z0  = __float2half(0.0f);
    const float x = ap[0], y = ap[1], z = ap[2];
    const float vx = -2.0f * x, vy = -2.0f * y, vz = -2.0f * z;
    __half Hx = __float2half(vx), Hy = __float2half(vy), Hz = __float2half(vz);
    __half Lx = __float2half((vx - __half2float(Hx)) * SC);
    __half Ly = __float2half((vy - __half2float(Hy)) * SC);
    __half Lz = __float2half((vz - __half2float(Hz)) * SC);
    __half Sx = __float2half(__half2float(Hx) * ISC);
    __half Sy = __float2half(__half2float(Hy) * ISC);
    __half Sz = __float2half(__half2float(Hz) * ISC);
    const float p2 = fmaf(x, x, fmaf(y, y, z * z));
    __half hp2 = __float2half(p2);
    __half lp2 = __float2half(p2 - __half2float(hp2));
    U4H8 A;
    if (g == 0)
        A.u = make_uint4(pk(Hx, Hy), pk(Hz, Lx), pk(Ly, Lz), pk(hp2, one));
    else
        A.u = make_uint4(pk(Sx, Sy), pk(Sz, lp2), pk(one, z0), pk(z0, z0));
    return A;
}

// Wave-private 32x33-stride LDS transpose + row-min + store.
#define EPILOGUE(acc, dstp)                                                   \
    {                                                                         \
        _Pragma("unroll")                                                     \
        for (int r = 0; r < 16; ++r) {                                        \
            const int row0 = (r & 3) + 8 * (r >> 2) + 4 * g;                  \
            sf[wbase + row0 * 33 + col] = acc[r];                             \
        }                                                                     \
        const float* rp = &sf[wbase + col * 33 + ch * 16];                    \
        float v = rp[0];                                                      \
        _Pragma("unroll")                                                     \
        for (int i = 1; i < 16; ++i) v = fminf(v, rp[i]);                     \
        v = fminf(v, __shfl_xor(v, 32, 64));                                  \
        if (L < 32) (dstp)[L] = v;                                            \
    }

__global__ __launch_bounds__(THREADS) void chamfer_mfma_kernel(
        const float* __restrict__ pc1, const float* __restrict__ pc2,
        float* __restrict__ part_row, float* __restrict__ part_col,
        float* __restrict__ out) {
    const int bid    = blockIdx.x;       // 4096 = batch*1024 + ichunk*32 + jchunk
    const int jchunk = bid & 31;
    const int ichunk = (bid >> 5) & 31;
    const int batch  = bid >> 10;

    if (bid == 0 && threadIdx.x < BATCH) out[threadIdx.x] = 0.0f;

    // LDS dwords: brecs [0..2047] (g0 p*4, g1 1024+p*4), arecs [2048..4095];
    // epilogue scratch [0..4223] (4 waves x 1056) aliases dead records.
    __shared__ unsigned smem[4224];
    unsigned* brecs = smem;
    unsigned* arecs = smem + 2048;

    const int t = threadIdx.x;
    const int L = t & 63;
    const int w = t >> 6;
    const int g = L >> 5;
    const int col = L & 31;
    const int ch = L >> 5;

    const float* abase = pc1 + (size_t)batch * NPTS * 3;
    const float* bbase = pc2 + (size_t)batch * NPTS * 3;
    const int i0 = ichunk * 256, j0 = jchunk * 256;

    // ---- cooperative stage: both record sets ----
    make_rec(bbase + 3 * (j0 + t), &brecs[t * 4], &brecs[1024 + t * 4]);
    make_rec(abase + 3 * (i0 + t), &arecs[t * 4], &arecs[1024 + t * 4]);

    // ---- pass-1 A-frags from a-points (rows i0 + w*64 + col + {0,32}) ----
    U4H8 A0 = make_afrag(abase + 3 * (i0 + w * 64 + col), g);
    U4H8 A1 = make_afrag(abase + 3 * (i0 + w * 64 + col + 32), g);

    float rm0[16], rm1[16];
    #pragma unroll
    for (int r = 0; r < 16; ++r) { rm0[r] = FLT_BIG; rm1[r] = FLT_BIG; }

    __syncthreads();

    const f32x16 zf = {0.0f};
    const int fb = g * 1024 + col * 4;

    // ---- pass 1: stream b-record tiles, rows = a ----
    {
        U4H8 nb; nb.u = *(const uint4*)&brecs[fb];
        #pragma unroll 2
        for (int jt = 0; jt < 8; ++jt) {
            const U4H8 b = nb;
            if (jt < 7) nb.u = *(const uint4*)&brecs[fb + (jt + 1) * 128];
            f32x16 d0 = __builtin_amdgcn_mfma_f32_32x32x16_f16(A0.h, b.h, zf, 0, 0, 0);
            f32x16 d1 = __builtin_amdgcn_mfma_f32_32x32x16_f16(A1.h, b.h, zf, 0, 0, 0);
            #pragma unroll
            for (int r = 0; r < 16; ++r) {
                rm0[r] = fminf(rm0[r], d0[r]);
                rm1[r] = fminf(rm1[r], d1[r]);
            }
        }
    }

    // ---- pass-2 A-frags from b-points; stream a-record tiles, rows = b ----
    A0 = make_afrag(bbase + 3 * (j0 + w * 64 + col), g);
    A1 = make_afrag(bbase + 3 * (j0 + w * 64 + col + 32), g);

    float cm0[16], cm1[16];
    #pragma unroll
    for (int r = 0; r < 16; ++r) { cm0[r] = FLT_BIG; cm1[r] = FLT_BIG; }

    {
        U4H8 na; na.u = *(const uint4*)&arecs[fb];
        #pragma unroll 2
        for (int it = 0; it < 8; ++it) {
            const U4H8 a = na;
            if (it < 7) na.u = *(const uint4*)&arecs[fb + (it + 1) * 128];
            f32x16 d0 = __builtin_amdgcn_mfma_f32_32x32x16_f16(A0.h, a.h, zf, 0, 0, 0);
            f32x16 d1 = __builtin_amdgcn_mfma_f32_32x32x16_f16(A1.h, a.h, zf, 0, 0, 0);
            #pragma unroll
            for (int r = 0; r < 16; ++r) {
                cm0[r] = fminf(cm0[r], d0[r]);
                cm1[r] = fminf(cm1[r], d1[r]);
            }
        }
    }

    __syncthreads();   // all record reads done; scratch may alias records

    // ---- epilogue: 4 sub-passes ----
    float* sf = (float*)smem;
    const int wbase = w * 1056;

    float* dr = part_row + ((size_t)batch * NCH + jchunk) * NPTS + i0 + w * 64;
    float* dc = part_col + ((size_t)batch * NCH + ichunk) * NPTS + j0 + w * 64;

    EPILOGUE(rm0, dr);
    EPILOGUE(rm1, dr + 32);
    EPILOGUE(cm0, dc);
    EPILOGUE(cm1, dc + 32);
}

__global__ __launch_bounds__(THREADS) void chamfer_reduce_kernel(
        const float* __restrict__ part_row, const float* __restrict__ part_col,
        float* __restrict__ out) {
    const int idx   = blockIdx.x * THREADS + threadIdx.x;   // 0..65535
    const int dir   = idx >> 15;
    const int batch = (idx >> 13) & 3;
    const int n     = idx & (NPTS - 1);

    const float* pb = (dir == 0 ? part_row : part_col) + (size_t)batch * NCH * NPTS + n;
    float m0 = FLT_BIG, m1 = FLT_BIG, m2 = FLT_BIG, m3 = FLT_BIG;
    #pragma unroll
    for (int s = 0; s < NCH; s += 4) {
        m0 = fminf(m0, pb[(size_t)(s + 0) * NPTS]);
        m1 = fminf(m1, pb[(size_t)(s + 1) * NPTS]);
        m2 = fminf(m2, pb[(size_t)(s + 2) * NPTS]);
        m3 = fminf(m3, pb[(size_t)(s + 3) * NPTS]);
    }
    float d2 = fmaxf(fminf(fminf(m0, m1), fminf(m2, m3)), 0.0f);

    #pragma unroll
    for (int off = 32; off > 0; off >>= 1)
        d2 += __shfl_down(d2, off, 64);

    __shared__ float wsum[THREADS / 64];
    if ((threadIdx.x & 63) == 0) wsum[threadIdx.x >> 6] = d2;
    __syncthreads();

    if (threadIdx.x == 0) {
        float ssum = 0.0f;
        #pragma unroll
        for (int wv = 0; wv < THREADS / 64; ++wv) ssum += wsum[wv];
        atomicAdd(&out[batch], ssum * (1.0f / (float)NPTS));
    }
}

extern "C" void kernel_launch(void* const* d_in, const int* in_sizes, int n_in,
                              void* d_out, int out_size, void* d_ws, size_t ws_size,
                              hipStream_t stream) {
    const float* pc1 = (const float*)d_in[0];
    const float* pc2 = (const float*)d_in[1];
    float* out      = (float*)d_out;
    float* part_row = (float*)d_ws;                              // 4 MB
    float* part_col = part_row + (size_t)BATCH * NCH * NPTS;     // 4 MB

    chamfer_mfma_kernel<<<BATCH * NCH * NCH, THREADS, 0, stream>>>(
        pc1, pc2, part_row, part_col, out);
    chamfer_reduce_kernel<<<(2 * BATCH * NPTS) / THREADS, THREADS, 0, stream>>>(
        part_row, part_col, out);
}

// Round 13
// 86.303 us; speedup vs baseline: 1.2173x; 1.1267x over previous
//
#include <hip/hip_runtime.h>
#include <hip/hip_fp16.h>
#include <math.h>

// Chamfer distance, B=4, N=M=8192, D=3, fp32, via f16 MFMA — SYMMETRIC d^2.
// Round 13: per-direction blocks (no intra-block double-compute), each block
// streams 1024 cols against 256 rows (4x overhead amortization vs R12), and
// col-tile PAIRS are min3-folded: one v_min3_f32 per 2 elements.
//
// R12 lessons kept: __launch_bounds__(256) (block-size only — default
// flat-work-group-size=1,1024 caps regs at 64+64 and spills; the waves-per-EU
// arg AGPR-spills accumulators), no pointer indirection on accumulator arrays.
//
// K=16 slot packing (A side | B side), measured absmax 0.0:
//  k0-2 : h(-2p)xyz        | h(q)xyz           (hi*hi cross)
//  k3-5 : l(-2p)xyz*2^8    | h(q)xyz*2^-8      (lo*hi)
//  k6   : h(p^2)           | 1
//  k7   : 1                | h(q^2)
//  k8-10: h(-2p)xyz*2^-8   | l(q)xyz*2^8       (hi*lo)
//  k11  : l(p^2)           | 1
//  k12  : 1                | l(q^2)            (dropped l*l ~2^-24)

#define BATCH   4
#define NPTS    8192
#define THREADS 256
#define CSL     1024          // cols streamed per block
#define NSLICE  (NPTS / CSL)  // 8
#define NRCH    (NPTS / 256)  // 32 row-chunks
#define SC      256.0f
#define ISC     (1.0f/256.0f)
#define FLT_BIG 3.4e38f

typedef _Float16 half8 __attribute__((ext_vector_type(8)));
typedef float f32x16 __attribute__((ext_vector_type(16)));

union U4H8 { uint4 u; half8 h; };

__device__ __forceinline__ unsigned pk(__half lo, __half hi) {
    return (unsigned)__half_as_ushort(lo) | ((unsigned)__half_as_ushort(hi) << 16);
}

// B-operand-format record for point q (coords +q, norm q^2 in the B slots)
__device__ __forceinline__ void make_rec(const float* __restrict__ src,
                                         unsigned* __restrict__ g0d,
                                         unsigned* __restrict__ g1d) {
    const __half one = __float2half(1.0f);
    const __half z0  = __float2half(0.0f);
    const float x = src[0], y = src[1], z = src[2];
    __half hx = __float2half(x), hy = __float2half(y), hz = __float2half(z);
    __half lx = __float2half((x - __half2float(hx)) * SC);
    __half ly = __float2half((y - __half2float(hy)) * SC);
    __half lz = __float2half((z - __half2float(hz)) * SC);
    __half sx = __float2half(__half2float(hx) * ISC);
    __half sy = __float2half(__half2float(hy) * ISC);
    __half sz = __float2half(__half2float(hz) * ISC);
    const float q2 = fmaf(x, x, fmaf(y, y, z * z));
    __half hq2 = __float2half(q2);
    __half lq2 = __float2half(q2 - __half2float(hq2));
    *(uint4*)g0d = make_uint4(pk(hx, hy), pk(hz, sx), pk(sy, sz), pk(one, hq2));
    *(uint4*)g1d = make_uint4(pk(lx, ly), pk(lz, one), pk(lq2, z0), pk(z0, z0));
}

// A-operand-format fragment for point p (coords -2p, norm p^2 in the A slots)
__device__ __forceinline__ U4H8 make_afrag(const float* __restrict__ ap, int g) {
    const __half one = __float2half(1.0f);
    const __half z0  = __float2half(0.0f);
    const float x = ap[0], y = ap[1], z = ap[2];
    const float vx = -2.0f * x, vy = -2.0f * y, vz = -2.0f * z;
    __half Hx = __float2half(vx), Hy = __float2half(vy), Hz = __float2half(vz);
    __half Lx = __float2half((vx - __half2float(Hx)) * SC);
    __half Ly = __float2half((vy - __half2float(Hy)) * SC);
    __half Lz = __float2half((vz - __half2float(Hz)) * SC);
    __half Sx = __float2half(__half2float(Hx) * ISC);
    __half Sy = __float2half(__half2float(Hy) * ISC);
    __half Sz = __float2half(__half2float(Hz) * ISC);
    const float p2 = fmaf(x, x, fmaf(y, y, z * z));
    __half hp2 = __float2half(p2);
    __half lp2 = __float2half(p2 - __half2float(hp2));
    U4H8 A;
    if (g == 0)
        A.u = make_uint4(pk(Hx, Hy), pk(Hz, Lx), pk(Ly, Lz), pk(hp2, one));
    else
        A.u = make_uint4(pk(Sx, Sy), pk(Sz, lp2), pk(one, z0), pk(z0, z0));
    return A;
}

// Wave-private 32x33-stride LDS transpose + row-min + store.
#define EPILOGUE(acc, dstp)                                                   \
    {                                                                         \
        _Pragma("unroll")                                                     \
        for (int r = 0; r < 16; ++r) {                                        \
            const int row0 = (r & 3) + 8 * (r >> 2) + 4 * g;                  \
            sf[wbase + row0 * 33 + col] = acc[r];                             \
        }                                                                     \
        const float* rp = &sf[wbase + col * 33 + ch * 16];                    \
        float v = rp[0];                                                      \
        _Pragma("unroll")                                                     \
        for (int i = 1; i < 16; ++i) v = fminf(v, rp[i]);                     \
        v = fminf(v, __shfl_xor(v, 32, 64));                                  \
        if (L < 32) (dstp)[L] = v;                                            \
    }

__global__ __launch_bounds__(THREADS) void chamfer_mfma_kernel(
        const float* __restrict__ pc1, const float* __restrict__ pc2,
        float* __restrict__ part, float* __restrict__ out) {
    const int bid    = blockIdx.x;   // 2048 = ((dir*4+batch)*32 + rchunk)*8 + cslice
    const int cslice = bid & 7;
    const int rchunk = (bid >> 3) & 31;
    const int batch  = (bid >> 8) & 3;
    const int dir    = bid >> 10;

    if (bid == 0 && threadIdx.x < BATCH) out[threadIdx.x] = 0.0f;

    const float* rbase = (dir ? pc2 : pc1) + (size_t)batch * NPTS * 3;
    const float* cbase = (dir ? pc1 : pc2) + (size_t)batch * NPTS * 3;
    const int r0 = rchunk * 256, c0 = cslice * CSL;

    // LDS dwords: records [0..8191] (g0 at p*4, g1 at 4096+p*4); epilogue
    // scratch (4 waves x 1056 = 4224 dw) aliases dead records after the loop.
    __shared__ unsigned smem[8192];

    const int t = threadIdx.x;
    const int L = t & 63;
    const int w = t >> 6;
    const int g = L >> 5;
    const int col = L & 31;
    const int ch = g;

    // ---- stage 1024 col-records (4 per thread) ----
    #pragma unroll
    for (int k = 0; k < 4; ++k) {
        const int p = k * THREADS + t;
        make_rec(cbase + 3 * (c0 + p), &smem[p * 4], &smem[4096 + p * 4]);
    }

    // ---- A fragments for this wave's 64 rows ----
    U4H8 A0 = make_afrag(rbase + 3 * (r0 + w * 64 + col), g);
    U4H8 A1 = make_afrag(rbase + 3 * (r0 + w * 64 + col + 32), g);

    float rm0[16], rm1[16];
    #pragma unroll
    for (int r = 0; r < 16; ++r) { rm0[r] = FLT_BIG; rm1[r] = FLT_BIG; }

    __syncthreads();

    const f32x16 zf = {0.0f};
    const int fb = g * 4096 + col * 4;

    // ---- main loop: 32 col-tiles in pairs, min3-folded ----
    U4H8 nb0, nb1;
    nb0.u = *(const uint4*)&smem[fb];
    nb1.u = *(const uint4*)&smem[fb + 128];
    for (int mt = 0; mt < 32; mt += 2) {
        const U4H8 b0 = nb0, b1 = nb1;
        if (mt + 2 < 32) {
            nb0.u = *(const uint4*)&smem[fb + (mt + 2) * 128];
            nb1.u = *(const uint4*)&smem[fb + (mt + 3) * 128];
        }
        f32x16 d0a = __builtin_amdgcn_mfma_f32_32x32x16_f16(A0.h, b0.h, zf, 0, 0, 0);
        f32x16 d0b = __builtin_amdgcn_mfma_f32_32x32x16_f16(A0.h, b1.h, zf, 0, 0, 0);
        f32x16 d1a = __builtin_amdgcn_mfma_f32_32x32x16_f16(A1.h, b0.h, zf, 0, 0, 0);
        f32x16 d1b = __builtin_amdgcn_mfma_f32_32x32x16_f16(A1.h, b1.h, zf, 0, 0, 0);
        #pragma unroll
        for (int r = 0; r < 16; ++r) {
            rm0[r] = fminf(fminf(d0a[r], d0b[r]), rm0[r]);   // v_min3_f32
            rm1[r] = fminf(fminf(d1a[r], d1b[r]), rm1[r]);
        }
    }

    __syncthreads();   // record reads done; scratch may alias records

    // ---- epilogue: 2 sub-passes ----
    float* sf = (float*)smem;
    const int wbase = w * 1056;
    float* dst = part + (((size_t)(dir * BATCH + batch)) * NSLICE + cslice) * NPTS
               + r0 + w * 64;

    EPILOGUE(rm0, dst);
    EPILOGUE(rm1, dst + 32);
}

__global__ __launch_bounds__(THREADS) void chamfer_reduce_kernel(
        const float* __restrict__ part, float* __restrict__ out) {
    const int idx   = blockIdx.x * THREADS + threadIdx.x;   // 0..65535
    const int dir   = idx >> 15;
    const int batch = (idx >> 13) & 3;
    const int n     = idx & (NPTS - 1);

    const float* pb = part + (size_t)(dir * BATCH + batch) * NSLICE * NPTS + n;
    float m0 = pb[0];
    float m1 = pb[(size_t)1 * NPTS];
    float m2 = pb[(size_t)2 * NPTS];
    float m3 = pb[(size_t)3 * NPTS];
    m0 = fminf(m0, pb[(size_t)4 * NPTS]);
    m1 = fminf(m1, pb[(size_t)5 * NPTS]);
    m2 = fminf(m2, pb[(size_t)6 * NPTS]);
    m3 = fminf(m3, pb[(size_t)7 * NPTS]);
    float d2 = fmaxf(fminf(fminf(m0, m1), fminf(m2, m3)), 0.0f);

    #pragma unroll
    for (int off = 32; off > 0; off >>= 1)
        d2 += __shfl_down(d2, off, 64);

    __shared__ float wsum[THREADS / 64];
    if ((threadIdx.x & 63) == 0) wsum[threadIdx.x >> 6] = d2;
    __syncthreads();

    if (threadIdx.x == 0) {
        float ssum = 0.0f;
        #pragma unroll
        for (int wv = 0; wv < THREADS / 64; ++wv) ssum += wsum[wv];
        atomicAdd(&out[batch], ssum * (1.0f / (float)NPTS));
    }
}

extern "C" void kernel_launch(void* const* d_in, const int* in_sizes, int n_in,
                              void* d_out, int out_size, void* d_ws, size_t ws_size,
                              hipStream_t stream) {
    const float* pc1 = (const float*)d_in[0];
    const float* pc2 = (const float*)d_in[1];
    float* out  = (float*)d_out;
    float* part = (float*)d_ws;     // 2*4*8*8192 floats = 2 MB

    chamfer_mfma_kernel<<<2 * BATCH * NRCH * NSLICE, THREADS, 0, stream>>>(
        pc1, pc2, part, out);
    chamfer_reduce_kernel<<<(2 * BATCH * NPTS) / THREADS, THREADS, 0, stream>>>(
        part, out);
}